// Round 4
// baseline (109.634 us; speedup 1.0000x reference)
//
#include <hip/hip_runtime.h>
#include <stdint.h>

#define W 768
#define NPROB (768*768)
#define NB 8
#define NBINS 2048
#define CAP 4096
#define TOPK 2048
#define SCORE_THR 0.6f
#define NBLK 36            // blocks per batch for scan kernels; NPROB = 36*16384
#define HASHN 8192
#define HEMPTY 0xFFFFFFFFu

// ws layout (bytes) — nothing needs pre-zeroing; every buffer is written before read
#define HPART_OFF  0
#define HPART_BYTES (NB*NBLK*NBINS*4)        // 2,359,296
#define META_OFF  (HPART_OFF + HPART_BYTES)
#define CAND_OFF  (META_OFF + 256)
#define CAND_BYTES (NB*CAP*8)                // 262,144
#define SKEY_OFF  (CAND_OFF + CAND_BYTES)
#define SKEY_BYTES (NB*TOPK*8)               // 131,072
#define WS_TOTAL  (SKEY_OFF + SKEY_BYTES)    // ~2.75 MB

struct Meta { unsigned bstar; unsigned c1; unsigned cnt; unsigned pad; };

// bin over float bits: valid scores are in [0.6,1.0) -> one binade, bits monotone
__device__ __forceinline__ unsigned score_bin(unsigned fb) {
    return (fb >> 13) & 0x7FFu;
}

// Per-block private histogram: plain stores, no pre-zero, no global atomics.
__global__ __launch_bounds__(256) void hist_kernel(const float* __restrict__ probs,
                                                   unsigned* __restrict__ hpart) {
    __shared__ unsigned lh[NBINS];
    int b = blockIdx.y;
    for (int i = threadIdx.x; i < NBINS; i += 256) lh[i] = 0;
    __syncthreads();
    const int per4 = (NPROB / NBLK) / 4;      // 4096 float4 per block
    const float4* p = (const float4*)(probs + (size_t)b * NPROB) + (size_t)blockIdx.x * per4;
    for (int i = threadIdx.x; i < per4; i += 256) {
        float4 v = p[i];
        if (v.x >= SCORE_THR) atomicAdd(&lh[score_bin(__float_as_uint(v.x))], 1u);
        if (v.y >= SCORE_THR) atomicAdd(&lh[score_bin(__float_as_uint(v.y))], 1u);
        if (v.z >= SCORE_THR) atomicAdd(&lh[score_bin(__float_as_uint(v.z))], 1u);
        if (v.w >= SCORE_THR) atomicAdd(&lh[score_bin(__float_as_uint(v.w))], 1u);
    }
    __syncthreads();
    unsigned* gh = hpart + ((size_t)b * NBLK + blockIdx.x) * NBINS;
    for (int i = threadIdx.x; i < NBINS; i += 256) gh[i] = lh[i];
}

// Reduce partials, find threshold bin, and reset meta.cnt for compact.
__global__ __launch_bounds__(256) void select_kernel(const unsigned* __restrict__ hpart,
                                                     Meta* __restrict__ meta) {
    int b = blockIdx.x;
    __shared__ unsigned hbin[NBINS];
    __shared__ unsigned partial[256];
    int t = threadIdx.x;
    // sum 36 partials per bin; consecutive threads -> consecutive bins (coalesced)
    for (int i = t; i < NBINS; i += 256) {
        unsigned s = 0;
        const unsigned* hp = hpart + (size_t)b * NBLK * NBINS + i;
        #pragma unroll 4
        for (int blk = 0; blk < NBLK; ++blk) s += hp[(size_t)blk * NBINS];
        hbin[i] = s;
    }
    __syncthreads();
    unsigned s = 0;
    #pragma unroll
    for (int i = 0; i < 8; ++i) s += hbin[t * 8 + i];
    partial[t] = s;
    __syncthreads();
    if (t == 0) {
        unsigned cum = 0;
        int chunk = 255;
        for (; chunk >= 0; --chunk) {
            if (cum + partial[chunk] >= TOPK) break;
            cum += partial[chunk];
        }
        unsigned bstar = 0, c1 = cum;
        if (chunk >= 0) {
            int bin = chunk * 8 + 7;
            for (; bin >= chunk * 8; --bin) {
                unsigned v = hbin[bin];
                if (cum + v >= TOPK) break;
                cum += v;
            }
            bstar = (unsigned)bin;
            c1 = cum;
        }
        meta[b].bstar = bstar;
        meta[b].c1 = c1;
        meta[b].cnt = 0;     // reset for compact (runs next in-stream)
    }
}

// Block-local compaction: float4 loads, LDS staging, ONE global atomic per block.
__global__ __launch_bounds__(256) void compact_kernel(const float* __restrict__ probs,
                                                      Meta* __restrict__ meta,
                                                      unsigned long long* __restrict__ cand) {
    __shared__ unsigned long long lbuf[CAP];   // 32 KB
    __shared__ unsigned lcnt;
    __shared__ unsigned gbase;
    int b = blockIdx.y;
    int tid = threadIdx.x;
    if (tid == 0) lcnt = 0;
    __syncthreads();

    unsigned bstar = meta[b].bstar;
    const int per4 = (NPROB / NBLK) / 4;
    int base_elem = blockIdx.x * (NPROB / NBLK);
    const float4* p = (const float4*)(probs + (size_t)b * NPROB) + (size_t)blockIdx.x * per4;
    for (int i = tid; i < per4; i += 256) {
        float4 v = p[i];
        int ei = base_elem + i * 4;
        float sv[4] = {v.x, v.y, v.z, v.w};
        #pragma unroll
        for (int c = 0; c < 4; ++c) {
            float s = sv[c];
            if (s >= SCORE_THR) {
                unsigned fb = __float_as_uint(s);
                if (score_bin(fb) >= bstar) {
                    unsigned pos = atomicAdd(&lcnt, 1u);   // LDS atomic
                    if (pos < CAP) {
                        unsigned idx = (unsigned)(ei + c);
                        lbuf[pos] = ((unsigned long long)fb << 32) | (unsigned)(~idx);
                    }
                }
            }
        }
    }
    __syncthreads();
    unsigned n = lcnt < CAP ? lcnt : CAP;
    if (tid == 0) gbase = atomicAdd(&meta[b].cnt, n);      // one global atomic per block
    __syncthreads();
    unsigned gb = gbase;
    unsigned long long* dst = cand + (size_t)b * CAP;
    for (unsigned i = tid; i < n; i += 256) {
        unsigned o = gb + i;
        if (o < CAP) dst[o] = lbuf[i];
    }
}

// Exact rank by counting: keys are unique (score bits + ~idx), so
// rank = #{y : y > x} reproduces jax top_k order exactly.
__global__ __launch_bounds__(256) void rank_kernel(const unsigned long long* __restrict__ cand,
                                                   const Meta* __restrict__ meta,
                                                   unsigned long long* __restrict__ skey) {
    int b = blockIdx.y;
    __shared__ unsigned long long k[CAP];   // 32 KB
    unsigned cnt = meta[b].cnt;
    int n = (int)(cnt < CAP ? cnt : CAP);
    int nload = (n + 255) & ~255;
    for (int i = threadIdx.x; i < nload; i += 256)
        k[i] = cand[(size_t)b * CAP + i];
    __syncthreads();
    int p = blockIdx.x * 256 + threadIdx.x;
    if (p < n) {
        unsigned long long key = k[p];
        int r = 0;
        int i = 0;
        #pragma unroll 4
        for (; i + 4 <= n; i += 4) {
            r += (k[i]   > key);
            r += (k[i+1] > key);
            r += (k[i+2] > key);
            r += (k[i+3] > key);
        }
        for (; i < n; ++i) r += (k[i] > key);
        if (r < TOPK) skey[(size_t)b * TOPK + r] = key;
    }
}

// Fused: LDS hash (cell->rank) for neighbor discovery (<=8 probes/box),
// monotone fixpoint NMS resolve, refine + write.
__global__ __launch_bounds__(1024) void nms_out_kernel(const float* __restrict__ dev4,
                                                       const unsigned long long* __restrict__ skey,
                                                       const Meta* __restrict__ meta,
                                                       float* __restrict__ out) {
    int b = blockIdx.x;
    __shared__ unsigned s_hash[HASHN];       // 32 KB
    __shared__ unsigned char s_state[TOPK];  // 0=undecided 1=kept 2=dead
    __shared__ int s_changed;
    int tid = threadIdx.x;

    unsigned cnt = meta[b].cnt;
    int nvalid = (int)(cnt < TOPK ? cnt : TOPK);

    for (int i = tid; i < HASHN; i += 1024) s_hash[i] = HEMPTY;
    __syncthreads();

    unsigned long long mykey[2];
    unsigned myidx[2];
    bool vld[2];
    #pragma unroll 2
    for (int q = 0; q < 2; ++q) {
        int j = tid + q * 1024;
        vld[q] = (j < nvalid);
        unsigned long long key = vld[q] ? skey[(size_t)b * TOPK + j] : 0ULL;
        mykey[q] = key;
        if (vld[q]) {
            unsigned idx = ~(unsigned)key;
            myidx[q] = idx;
            unsigned val = (idx << 11) | (unsigned)j;   // idx<2^20, j<2^11
            unsigned slot = (idx * 2654435761u >> 19) & (HASHN - 1);
            while (true) {
                unsigned old = atomicCAS(&s_hash[slot], HEMPTY, val);
                if (old == HEMPTY) break;
                slot = (slot + 1) & (HASHN - 1);
            }
        } else {
            myidx[q] = 0;
        }
    }
    __syncthreads();

    // neighbor discovery: 8 surrounding cells, keep earlier ranks (packed 4x16b in 2 u64)
    const int DY[8] = {-1,-1,-1, 0, 0, 1, 1, 1};
    const int DX[8] = {-1, 0, 1,-1, 1,-1, 0, 1};
    unsigned long long np0[2] = {0,0}, np1[2] = {0,0};
    int nc[2] = {0,0};
    #pragma unroll 2
    for (int q = 0; q < 2; ++q) {
        int j = tid + q * 1024;
        if (vld[q]) {
            int y = (int)(myidx[q] / W), x = (int)(myidx[q] % W);
            int cnt2 = 0;
            unsigned long long l0 = 0, l1 = 0;
            #pragma unroll
            for (int t = 0; t < 8; ++t) {
                int ny = y + DY[t], nx = x + DX[t];
                if ((unsigned)ny < (unsigned)W && (unsigned)nx < (unsigned)W) {
                    unsigned cell = (unsigned)(ny * W + nx);
                    unsigned slot = (cell * 2654435761u >> 19) & (HASHN - 1);
                    int r = -1;
                    while (true) {
                        unsigned v = s_hash[slot];
                        if (v == HEMPTY) break;
                        if ((v >> 11) == cell) { r = (int)(v & 2047u); break; }
                        slot = (slot + 1) & (HASHN - 1);
                    }
                    if (r >= 0 && r < j) {
                        if (cnt2 < 4)      l0 |= (unsigned long long)(unsigned)r << (cnt2 * 16);
                        else               l1 |= (unsigned long long)(unsigned)r << ((cnt2 - 4) * 16);
                        cnt2++;
                    }
                }
            }
            np0[q] = l0; np1[q] = l1; nc[q] = cnt2;
        }
        unsigned char st;
        if (!vld[q]) st = 2;
        else st = (nc[q] == 0) ? 1 : 0;
        s_state[j] = st;
    }
    __syncthreads();

    // fixpoint: states move monotonically 0 -> {1,2}; unique fixpoint == greedy NMS
    while (true) {
        __syncthreads();
        if (tid == 0) s_changed = 0;
        __syncthreads();
        bool ch = false;
        #pragma unroll 2
        for (int q = 0; q < 2; ++q) {
            int j = tid + q * 1024;
            if (s_state[j] == 0) {
                bool anyKept = false, anyUnd = false;
                int c = nc[q];
                #pragma unroll
                for (int l = 0; l < 8; ++l) {
                    if (l < c) {
                        unsigned r = (l < 4)
                            ? (unsigned)((np0[q] >> (l * 16)) & 0xFFFFu)
                            : (unsigned)((np1[q] >> ((l - 4) * 16)) & 0xFFFFu);
                        unsigned char st = s_state[r];
                        anyKept |= (st == 1);
                        anyUnd  |= (st == 0);
                    }
                }
                if (anyKept)      { s_state[j] = 2; ch = true; }
                else if (!anyUnd) { s_state[j] = 1; ch = true; }
            }
        }
        if (ch) s_changed = 1;
        __syncthreads();
        if (s_changed == 0) break;
    }

    // refine + write (all TOPK*5 outputs written unconditionally)
    #pragma unroll 2
    for (int q = 0; q < 2; ++q) {
        int j = tid + q * 1024;
        float o0 = 0.f, o1 = 0.f, o2 = 0.f, o3 = 0.f, o4 = 0.f;
        if (vld[q] && s_state[j] == 1) {
            unsigned idx = myidx[q];
            float sc = __uint_as_float((unsigned)(mykey[q] >> 32));
            int y = (int)(idx / W), x = (int)(idx % W);
            const float4 d = ((const float4*)dev4)[(size_t)b * NPROB + idx];
            float b0 = (float)(4 * y + 2);
            float b1 = (float)(4 * x + 2);
            float b2 = (float)(4 * y + 24);
            float b3 = (float)(4 * x + 24);
            float r0 = b0 + d.x * 22.0f;
            float r1 = b1 + d.y * 22.0f;
            float r2 = b2 + d.z * 22.0f;
            float r3 = b3 + d.w * 22.0f;
            float rh = r2 - r0, rw = r3 - r1;
            float len = fmaxf(rh, rw);
            float c0 = r0 + rh * 0.5f, c1v = r1 + rw * 0.5f;
            float u0 = c0 - 0.5f * len, u1 = c1v - 0.5f * len;
            float v0 = u0 + len, v1 = u1 + len;
            o0 = fminf(fmaxf(u0, 1.0f), 3095.0f);
            o1 = fminf(fmaxf(u1, 1.0f), 3095.0f);
            o2 = fminf(fmaxf(v0, 1.0f), 3095.0f);
            o3 = fminf(fmaxf(v1, 1.0f), 3095.0f);
            o4 = sc;
        }
        float* op = out + ((size_t)b * TOPK + j) * 5;
        op[0] = o0; op[1] = o1; op[2] = o2; op[3] = o3; op[4] = o4;
    }
}

extern "C" void kernel_launch(void* const* d_in, const int* in_sizes, int n_in,
                              void* d_out, int out_size, void* d_ws, size_t ws_size,
                              hipStream_t stream) {
    (void)in_sizes; (void)n_in; (void)out_size;
    if (ws_size < (size_t)WS_TOTAL) return;

    const float* probs = (const float*)d_in[0];
    const float* devs  = (const float*)d_in[1];
    float* out = (float*)d_out;
    char* ws = (char*)d_ws;

    unsigned* hpart = (unsigned*)(ws + HPART_OFF);
    Meta* meta = (Meta*)(ws + META_OFF);
    unsigned long long* cand = (unsigned long long*)(ws + CAND_OFF);
    unsigned long long* skey = (unsigned long long*)(ws + SKEY_OFF);

    hist_kernel<<<dim3(NBLK, NB), 256, 0, stream>>>(probs, hpart);
    select_kernel<<<NB, 256, 0, stream>>>(hpart, meta);
    compact_kernel<<<dim3(NBLK, NB), 256, 0, stream>>>(probs, meta, cand);
    rank_kernel<<<dim3(CAP / 256, NB), 256, 0, stream>>>(cand, meta, skey);
    nms_out_kernel<<<NB, 1024, 0, stream>>>(devs, skey, meta, out);
}